// Round 2
// baseline (211.146 us; speedup 1.0000x reference)
//
#include <hip/hip_runtime.h>

// RoiAlign fused: level-select + crop_and_resize(7x7 bilinear, extrap 0)
// feat0: [B,256,256,256] f32 NHWC ; feat1: [B,128,128,256] f32 ; rois: [B,R,5]
// out: [B,R,7,7,256] f32
//
// Mapping: one wave (64 lanes) per (box n, pool row i); lane -> 4 channels
// via float4. Thread loops j=0..6 with a wave-uniform 2-column register
// cache (monotone xs => 2 entries capture all reuse). All global accesses
// are 16B/lane coalesced (1 KiB per wave per request).

#define POOL 7
#define NCH 256

// native vector type for nontemporal store (HIP float4 class is rejected)
typedef float nfloat4 __attribute__((ext_vector_type(4)));

__global__ __launch_bounds__(256) void roialign_kernel(
    const float* __restrict__ feat0,
    const float* __restrict__ feat1,
    const float* __restrict__ rois,
    float* __restrict__ out,
    int NB, int R) // NB = B*R
{
    int t = blockIdx.x * blockDim.x + threadIdx.x;
    int lane = t & 63;          // channel group: channels [4*lane, 4*lane+3]
    int wid  = t >> 6;          // n*7 + i   (wave-uniform)
    int n    = wid / 7;
    if (n >= NB) return;
    int i = wid - n * 7;

    const float* roi = rois + (size_t)n * 5;
    float y1 = roi[0], x1 = roi[1], y2 = roi[2], x2 = roi[3];

    // level select on RAW box coords (before normalization), matching ref
    bool lvl = (y2 - y1 > 48.0f) || (x2 - x1 > 48.0f);
    const float* feat = lvl ? feat1 : feat0;
    int H = lvl ? 128 : 256;
    int W = H;
    int b = n / R;

    const float inv_img = 1.0f / 1024.0f;
    float y1n = y1 * inv_img, y2n = y2 * inv_img;
    float x1n = x1 * inv_img, x2n = x2 * inv_img;

    float Hm1 = (float)(H - 1), Wm1 = (float)(W - 1);

    // ys = (y1n + (i/6)*(y2n-y1n)) * (H-1)   -- same op order as reference
    float ry = (float)i / 6.0f;
    float ys = (y1n + ry * (y2n - y1n)) * Hm1;
    float y0f = floorf(ys);
    float wy  = ys - y0f;
    int y0 = (int)fminf(fmaxf(y0f,        0.0f), Hm1);
    int yp = (int)fminf(fmaxf(y0f + 1.0f, 0.0f), Hm1);
    bool vy = (ys >= 0.0f) && (ys <= Hm1);

    size_t plane = (size_t)b * H * W;
    int coff = lane * 4;
    const float* row0 = feat + (plane + (size_t)y0 * W) * NCH + coff;
    const float* row1 = feat + (plane + (size_t)yp * W) * NCH + coff;

    float* orow = out + ((size_t)n * 49 + (size_t)i * POOL) * NCH + coff;

    float wy1 = 1.0f - wy;

    // 2-column register cache; indices are wave-uniform -> scalar branches
    int cx0 = -1, cxp = -1;
    float4 v00 = make_float4(0.f, 0.f, 0.f, 0.f);
    float4 v10 = v00, v01 = v00, v11 = v00;

    #pragma unroll
    for (int j = 0; j < POOL; ++j) {
        float rx = (float)j / 6.0f;                 // exact same rounding as ref
        float xs = (x1n + rx * (x2n - x1n)) * Wm1;
        float x0f = floorf(xs);
        float wx  = xs - x0f;
        int x0 = (int)fminf(fmaxf(x0f,        0.0f), Wm1);
        int xp = (int)fminf(fmaxf(x0f + 1.0f, 0.0f), Wm1);
        bool vx = (xs >= 0.0f) && (xs <= Wm1);

        // left column
        if (x0 != cx0) {
            if (x0 == cxp) { v00 = v01; v10 = v11; }   // shift right->left
            else {
                v00 = *(const float4*)(row0 + (size_t)x0 * NCH);
                v10 = *(const float4*)(row1 + (size_t)x0 * NCH);
            }
            cx0 = x0;
        }
        // right column (xp >= x0; equals x0 only at clip boundaries)
        if (xp != cxp) {
            if (xp == cx0) { v01 = v00; v11 = v10; }
            else {
                v01 = *(const float4*)(row0 + (size_t)xp * NCH);
                v11 = *(const float4*)(row1 + (size_t)xp * NCH);
            }
            cxp = xp;
        }

        float wx1 = 1.0f - wx;
        float4 o;
        {
            float tx = v00.x * wx1 + v01.x * wx;
            float bx = v10.x * wx1 + v11.x * wx;
            o.x = tx * wy1 + bx * wy;
            float ty = v00.y * wx1 + v01.y * wx;
            float by = v10.y * wx1 + v11.y * wx;
            o.y = ty * wy1 + by * wy;
            float tz = v00.z * wx1 + v01.z * wx;
            float bz = v10.z * wx1 + v11.z * wx;
            o.z = tz * wy1 + bz * wy;
            float tw = v00.w * wx1 + v01.w * wx;
            float bw = v10.w * wx1 + v11.w * wx;
            o.w = tw * wy1 + bw * wy;
        }
        if (!(vy && vx)) { o.x = 0.0f; o.y = 0.0f; o.z = 0.0f; o.w = 0.0f; }

        // write-once output: nontemporal, keep L2/L3 for feature maps
        nfloat4 ov;
        ov.x = o.x; ov.y = o.y; ov.z = o.z; ov.w = o.w;
        __builtin_nontemporal_store(ov, (nfloat4*)(orow + (size_t)j * NCH));
    }
}

extern "C" void kernel_launch(void* const* d_in, const int* in_sizes, int n_in,
                              void* d_out, int out_size, void* d_ws, size_t ws_size,
                              hipStream_t stream) {
    const float* feat0 = (const float*)d_in[0];
    const float* feat1 = (const float*)d_in[1];
    const float* rois  = (const float*)d_in[2];
    float* out = (float*)d_out;

    // B from feat0 size [B,256,256,256]; R from rois size [B,R,5]
    int B  = in_sizes[0] / (256 * 256 * 256);
    int NB = in_sizes[2] / 5;        // B*R boxes
    int R  = NB / B;

    // one wave per (box, pool row): NB*7 waves, 64 lanes each
    long long threads = (long long)NB * POOL * 64;
    int block = 256;
    int grid = (int)((threads + block - 1) / block);
    roialign_kernel<<<grid, block, 0, stream>>>(feat0, feat1, rois, out, NB, R);
}

// Round 4
// 207.671 us; speedup vs baseline: 1.0167x; 1.0167x over previous
//
#include <hip/hip_runtime.h>

// RoiAlign fused: level-select + crop_and_resize(7x7 bilinear, extrap 0)
// feat0: [B,256,256,256] f32 NHWC ; feat1: [B,128,128,256] f32 ; rois: [B,R,5]
// out: [B,R,7,7,256] f32
//
// Mapping: one wave (64 lanes) per (box n, pool row i); lane -> 4 channels
// via float4. ALL 28 corner loads are issued branch-free up front (phase 1),
// then bilinear compute + stores (phase 2). Duplicate column loads across j
// are absorbed by L1 (per-wave working set <= ~17 KiB < 32 KiB L1), so HBM
// traffic matches the dedup'd version while memory-level parallelism is 28
// loads in flight per wave instead of ~1.4.

#define POOL 7
#define NCH 256

// native vector type for nontemporal store (HIP float4 class is rejected)
typedef float nfloat4 __attribute__((ext_vector_type(4)));

__global__ __launch_bounds__(256) void roialign_kernel(
    const float* __restrict__ feat0,
    const float* __restrict__ feat1,
    const float* __restrict__ rois,
    float* __restrict__ out,
    int NB, int R) // NB = B*R
{
    int t = blockIdx.x * blockDim.x + threadIdx.x;
    int lane = t & 63;          // channel group: channels [4*lane, 4*lane+3]
    int wid  = t >> 6;          // n*7 + i   (wave-uniform)
    int n    = wid / 7;
    if (n >= NB) return;
    int i = wid - n * 7;

    const float* roi = rois + (size_t)n * 5;
    float y1 = roi[0], x1 = roi[1], y2 = roi[2], x2 = roi[3];

    // level select on RAW box coords (before normalization), matching ref
    bool lvl = (y2 - y1 > 48.0f) || (x2 - x1 > 48.0f);
    const float* feat = lvl ? feat1 : feat0;
    int H = lvl ? 128 : 256;
    int W = H;
    int b = n / R;

    const float inv_img = 1.0f / 1024.0f;
    float y1n = y1 * inv_img, y2n = y2 * inv_img;
    float x1n = x1 * inv_img, x2n = x2 * inv_img;

    float Hm1 = (float)(H - 1), Wm1 = (float)(W - 1);

    // ys = (y1n + (i/6)*(y2n-y1n)) * (H-1)   -- same op order as reference
    float ry = (float)i / 6.0f;
    float ys = (y1n + ry * (y2n - y1n)) * Hm1;
    float y0f = floorf(ys);
    float wy  = ys - y0f;
    int y0 = (int)fminf(fmaxf(y0f,        0.0f), Hm1);
    int yp = (int)fminf(fmaxf(y0f + 1.0f, 0.0f), Hm1);
    bool vy = (ys >= 0.0f) && (ys <= Hm1);

    size_t plane = (size_t)b * H * W;
    int coff = lane * 4;
    const float* row0 = feat + (plane + (size_t)y0 * W) * NCH + coff;
    const float* row1 = feat + (plane + (size_t)yp * W) * NCH + coff;

    float* orow = out + ((size_t)n * 49 + (size_t)i * POOL) * NCH + coff;

    float wy1 = 1.0f - wy;

    // ---- phase 0: x geometry for all j (branch-free, wave-uniform) ----
    float wxv[POOL];
    bool  vxv[POOL];
    int   x0v[POOL], xpv[POOL];
    #pragma unroll
    for (int j = 0; j < POOL; ++j) {
        float rx = (float)j / 6.0f;                 // exact same rounding as ref
        float xs = (x1n + rx * (x2n - x1n)) * Wm1;
        float x0f = floorf(xs);
        wxv[j] = xs - x0f;
        x0v[j] = (int)fminf(fmaxf(x0f,        0.0f), Wm1);
        xpv[j] = (int)fminf(fmaxf(x0f + 1.0f, 0.0f), Wm1);
        vxv[j] = (xs >= 0.0f) && (xs <= Wm1);
    }

    // ---- phase 1: issue all 28 corner loads (independent, max MLP) ----
    float4 v00[POOL], v01[POOL], v10[POOL], v11[POOL];
    #pragma unroll
    for (int j = 0; j < POOL; ++j) {
        v00[j] = *(const float4*)(row0 + (size_t)x0v[j] * NCH);
        v01[j] = *(const float4*)(row0 + (size_t)xpv[j] * NCH);
        v10[j] = *(const float4*)(row1 + (size_t)x0v[j] * NCH);
        v11[j] = *(const float4*)(row1 + (size_t)xpv[j] * NCH);
    }

    // ---- phase 2: bilinear + store ----
    #pragma unroll
    for (int j = 0; j < POOL; ++j) {
        float wx  = wxv[j];
        float wx1 = 1.0f - wx;
        float4 a = v00[j], bq = v01[j], c = v10[j], d = v11[j];
        float4 o;
        {
            float tx = a.x * wx1 + bq.x * wx;
            float bx = c.x * wx1 + d.x * wx;
            o.x = tx * wy1 + bx * wy;
            float ty = a.y * wx1 + bq.y * wx;
            float by = c.y * wx1 + d.y * wx;
            o.y = ty * wy1 + by * wy;
            float tz = a.z * wx1 + bq.z * wx;
            float bz = c.z * wx1 + d.z * wx;
            o.z = tz * wy1 + bz * wy;
            float tw = a.w * wx1 + bq.w * wx;
            float bw = c.w * wx1 + d.w * wx;
            o.w = tw * wy1 + bw * wy;
        }
        if (!(vy && vxv[j])) { o.x = 0.0f; o.y = 0.0f; o.z = 0.0f; o.w = 0.0f; }

        // write-once output: nontemporal, keep L2/L3 for feature maps
        nfloat4 ov;
        ov.x = o.x; ov.y = o.y; ov.z = o.z; ov.w = o.w;
        __builtin_nontemporal_store(ov, (nfloat4*)(orow + (size_t)j * NCH));
    }
}

extern "C" void kernel_launch(void* const* d_in, const int* in_sizes, int n_in,
                              void* d_out, int out_size, void* d_ws, size_t ws_size,
                              hipStream_t stream) {
    const float* feat0 = (const float*)d_in[0];
    const float* feat1 = (const float*)d_in[1];
    const float* rois  = (const float*)d_in[2];
    float* out = (float*)d_out;

    // B from feat0 size [B,256,256,256]; R from rois size [B,R,5]
    int B  = in_sizes[0] / (256 * 256 * 256);
    int NB = in_sizes[2] / 5;        // B*R boxes
    int R  = NB / B;

    // one wave per (box, pool row): NB*7 waves, 64 lanes each
    long long threads = (long long)NB * POOL * 64;
    int block = 256;
    int grid = (int)((threads + block - 1) / block);
    roialign_kernel<<<grid, block, 0, stream>>>(feat0, feat1, rois, out, NB, R);
}